// Round 16
// baseline (72.311 us; speedup 1.0000x reference)
//
#include <hip/hip_runtime.h>

typedef _Float16 half4v __attribute__((ext_vector_type(4)));
typedef __fp16 fp16x2 __attribute__((ext_vector_type(2)));
typedef float float4v __attribute__((ext_vector_type(4)));

#define S_ 1024
#define H_ 8
#define B_ 8
#define BH 64           // B*H
#define NROW 8192       // B*S
#define E_ 64
#define VST 1032        // vT row stride (halves)
#define VHALVES (9 * VST)        // 9288 halves = 18576 B per bh
#define VCHUNK (VHALVES / 8)     // 1161 uint4 chunks

// Pack 4 floats -> half4v via v_cvt_pkrtz_f16_f32.
static __device__ inline half4v pack4(float a, float b, float c, float d) {
    union { fp16x2 f2[2]; half4v h4; } u;
    u.f2[0] = __builtin_amdgcn_cvt_pkrtz(a, b);
    u.f2[1] = __builtin_amdgcn_cvt_pkrtz(c, d);
    return u.h4;
}

// ---------------------------------------------------------------------------
// proj_kernel (R15): closed-form quantum heads ONCE per (b,h) -> global
// kF/vT LDS images. proj_w = prod_{i=0..w} cos(x_i+th_i); proj_0 = prod_{1..7}.
// ---------------------------------------------------------------------------
__global__ __launch_bounds__(256) void proj_kernel(
        const float* __restrict__ x, const float* __restrict__ theta,
        _Float16* __restrict__ kG, _Float16* __restrict__ vG) {
    int bh = blockIdx.x >> 2;
    int s  = ((blockIdx.x & 3) << 8) + threadIdx.x;
    int b = bh >> 3, h = bh & 7;

    const float4* xp = (const float4*)(x + (((size_t)(b << 10) + s) << 6) + (h << 3));
    float4 x0 = xp[0];
    float4 x1 = xp[1];
    float c0 = __cosf(x0.x + theta[0]);
    float c1 = __cosf(x0.y + theta[1]);
    float c2 = __cosf(x0.z + theta[2]);
    float c3 = __cosf(x0.w + theta[3]);
    float c4 = __cosf(x1.x + theta[4]);
    float c5 = __cosf(x1.y + theta[5]);
    float c6 = __cosf(x1.z + theta[6]);
    float c7 = __cosf(x1.w + theta[7]);
    float e1 = c0 * c1;
    float e2 = e1 * c2;
    float e3 = e2 * c3;
    float e4 = e3 * c4;
    float e5 = e4 * c5;
    float e6 = e5 * c6;
    float e7 = e6 * c7;
    float e0 = ((c1 * c2) * (c3 * c4)) * ((c5 * c6) * c7);
    half4v lo = pack4(e0, e1, e2, e3);
    half4v hi = pack4(e4, e5, e6, e7);

    _Float16* kgb = kG + (size_t)bh * 8192;
    _Float16* vgb = vG + (size_t)bh * VHALVES;
    int kt = s >> 4, c = s & 15;
    *(half4v*)&kgb[kt * 128 + c * 4]      = lo;
    *(half4v*)&kgb[kt * 128 + 64 + c * 4] = hi;
    vgb[0 * VST + s] = lo[0]; vgb[1 * VST + s] = lo[1];
    vgb[2 * VST + s] = lo[2]; vgb[3 * VST + s] = lo[3];
    vgb[4 * VST + s] = hi[0]; vgb[5 * VST + s] = hi[1];
    vgb[6 * VST + s] = hi[2]; vgb[7 * VST + s] = hi[3];
    if ((blockIdx.x & 3) == 0) {
        const half4v one = {(_Float16)1.f, (_Float16)1.f, (_Float16)1.f, (_Float16)1.f};
        *(half4v*)&vgb[8 * VST + threadIdx.x * 4] = one;
    }
}

// ---------------------------------------------------------------------------
// attn_kernel R16: SPLIT-K WITHIN BLOCK. Wave w handles ALL FOUR q-tiles of
// the block but only key-quarter w (kt = w*16+i). Per kt: ONE K-frag read +
// ONE V-frag read serve 8 MFMAs + 16 exps (R10 used 8 reads for the same
// compute) -> per-wave LDS reads 128 -> 32. Chain ILP unchanged (4
// independent q-tile chains per kt). Cross-wave reduction of the 4 key-
// quarter partials through a 16 KB LDS buffer (reuses kF space, after a
// barrier). Numerics identical: P = exp2(S) no shift, O^T formulation,
// ones-row l-trick, mirror tricks for lanes 32..63 / cols 9..15.
// Grid (64,16)=1024 blocks = 4 blocks/CU (LDS 35 KB), 16 waves/CU.
// ---------------------------------------------------------------------------
__global__ __launch_bounds__(256, 4) void attn_kernel(
        const _Float16* __restrict__ kG, const _Float16* __restrict__ vG,
        _Float16* __restrict__ attnH) {
    __shared__ _Float16 kF[64 * 128];       // 16384 B (reused as reduction buf)
    __shared__ _Float16 vT[VHALVES];        // 18576 B
    int bh = blockIdx.x;
    int b = bh >> 3, h = bh & 7;
    int tid = threadIdx.x;

    // ---- stage: vector copy of precomputed images ----
    {
        const uint4* kg4 = (const uint4*)(kG + (size_t)bh * 8192);
        uint4* kf4 = (uint4*)kF;
#pragma unroll
        for (int i = 0; i < 4; ++i) kf4[tid + i * 256] = kg4[tid + i * 256];
        const uint4* vg4 = (const uint4*)(vG + (size_t)bh * VHALVES);
        uint4* vt4 = (uint4*)vT;
#pragma unroll
        for (int i = 0; i < 4; ++i) vt4[tid + i * 256] = vg4[tid + i * 256];
        if (tid < VCHUNK - 1024) vt4[tid + 1024] = vg4[tid + 1024];
    }
    __syncthreads();

    int lane = tid & 63;
    int wv   = tid >> 6;                    // wave = key-quarter
    int col  = lane & 15;
    int quad = lane >> 4;
    bool lo2 = (quad < 2);

    int kbase = (lane & 31) * 4;
    int vcol = (col < 9) ? col : (col - 8);
    int vbase = vcol * VST + quad * 4;
    int qt0 = blockIdx.y << 2;              // base q-tile (4 tiles per block)

    // Q-frags for all 4 q-tiles (quads>=2 ZERO kills K-frag mirror garbage)
    half4v qf0 = {(_Float16)0.f, (_Float16)0.f, (_Float16)0.f, (_Float16)0.f};
    half4v qf1 = qf0, qf2 = qf0, qf3 = qf0;
    if (lo2) {
        qf0 = *(const half4v*)&kF[kbase + (qt0 + 0) * 128];
        qf1 = *(const half4v*)&kF[kbase + (qt0 + 1) * 128];
        qf2 = *(const half4v*)&kF[kbase + (qt0 + 2) * 128];
        qf3 = *(const half4v*)&kF[kbase + (qt0 + 3) * 128];
    }
    const _Float16 qs = (_Float16)0.51012921f;  // log2(e)/sqrt(8)
    qf0 *= qs; qf1 *= qs; qf2 *= qs; qf3 *= qs;

    const float4v zc = {0.f, 0.f, 0.f, 0.f};
    float4v o0 = zc, o1 = zc, o2 = zc, o3 = zc;

#pragma unroll
    for (int i = 0; i < 16; ++i) {
        int kt = (wv << 4) + i;             // this wave's key quarter
        half4v kf = *(const half4v*)&kF[kbase + kt * 128];
        half4v vf = *(const half4v*)&vT[vbase + kt * 16];
        float4v s0 = __builtin_amdgcn_mfma_f32_16x16x16f16(kf, qf0, zc, 0, 0, 0);
        float4v s1 = __builtin_amdgcn_mfma_f32_16x16x16f16(kf, qf1, zc, 0, 0, 0);
        float4v s2 = __builtin_amdgcn_mfma_f32_16x16x16f16(kf, qf2, zc, 0, 0, 0);
        float4v s3 = __builtin_amdgcn_mfma_f32_16x16x16f16(kf, qf3, zc, 0, 0, 0);
        half4v p0 = pack4(__builtin_amdgcn_exp2f(s0[0]), __builtin_amdgcn_exp2f(s0[1]),
                          __builtin_amdgcn_exp2f(s0[2]), __builtin_amdgcn_exp2f(s0[3]));
        half4v p1 = pack4(__builtin_amdgcn_exp2f(s1[0]), __builtin_amdgcn_exp2f(s1[1]),
                          __builtin_amdgcn_exp2f(s1[2]), __builtin_amdgcn_exp2f(s1[3]));
        half4v p2 = pack4(__builtin_amdgcn_exp2f(s2[0]), __builtin_amdgcn_exp2f(s2[1]),
                          __builtin_amdgcn_exp2f(s2[2]), __builtin_amdgcn_exp2f(s2[3]));
        half4v p3 = pack4(__builtin_amdgcn_exp2f(s3[0]), __builtin_amdgcn_exp2f(s3[1]),
                          __builtin_amdgcn_exp2f(s3[2]), __builtin_amdgcn_exp2f(s3[3]));
        o0 = __builtin_amdgcn_mfma_f32_16x16x16f16(vf, p0, o0, 0, 0, 0);
        o1 = __builtin_amdgcn_mfma_f32_16x16x16f16(vf, p1, o1, 0, 0, 0);
        o2 = __builtin_amdgcn_mfma_f32_16x16x16f16(vf, p2, o2, 0, 0, 0);
        o3 = __builtin_amdgcn_mfma_f32_16x16x16f16(vf, p3, o3, 0, 0, 0);
    }

    // ---- cross-wave reduction: sum the 4 key-quarter partials per q-tile ----
    __syncthreads();                        // all kF reads done; reuse as buffer
    float* red = (float*)kF;                // 16 slots x 64 lanes x float4 = 16 KB
    *(float4v*)&red[(((wv << 2) + 0) * 64 + lane) << 2] = o0;
    *(float4v*)&red[(((wv << 2) + 1) * 64 + lane) << 2] = o1;
    *(float4v*)&red[(((wv << 2) + 2) * 64 + lane) << 2] = o2;
    *(float4v*)&red[(((wv << 2) + 3) * 64 + lane) << 2] = o3;
    __syncthreads();
    // wave wv finalizes q-tile wv (output mapping identical to R10/R15)
    float4v oacc = *(const float4v*)&red[((0 * 4 + wv) * 64 + lane) << 2]
                 + *(const float4v*)&red[((1 * 4 + wv) * 64 + lane) << 2]
                 + *(const float4v*)&red[((2 * 4 + wv) * 64 + lane) << 2]
                 + *(const float4v*)&red[((3 * 4 + wv) * 64 + lane) << 2];

    int q0 = (blockIdx.y << 6) + (wv << 4);
    float l = __shfl(oacc[0], 32 | col, 64);
    if (lo2) {
        float inv = __builtin_amdgcn_rcpf(l);
        half4v ov = pack4(oacc[0] * inv, oacc[1] * inv, oacc[2] * inv, oacc[3] * inv);
        *(half4v*)(attnH + (((size_t)(b << 10) + q0 + col) << 6) + (h << 3) + quad * 4) = ov;
    }
}

// ---------------------------------------------------------------------------
// combine (R14): zero LDS / zero barriers, direct-from-global fragments.
// ---------------------------------------------------------------------------
__global__ __launch_bounds__(64) void combine_kernel(
        const _Float16* __restrict__ AH, const float* __restrict__ W,
        float* __restrict__ out) {
    int r0 = blockIdx.x * 16;
    int lane = threadIdx.x;
    int col = lane & 15;
    int quad = lane >> 4;

    half4v af[4];
#pragma unroll
    for (int t = 0; t < 4; ++t)
        af[t] = *(const half4v*)&AH[(size_t)(r0 + col) * 64 + t * 16 + quad * 4];

    float4v acc[4] = {{0,0,0,0},{0,0,0,0},{0,0,0,0},{0,0,0,0}};
#pragma unroll
    for (int e = 0; e < 4; ++e) {
#pragma unroll
        for (int t = 0; t < 4; ++t) {
            float4 w4 = *(const float4*)&W[(size_t)(e * 16 + col) * 64 + t * 16 + quad * 4];
            half4v wf = {(_Float16)w4.x, (_Float16)w4.y, (_Float16)w4.z, (_Float16)w4.w};
            acc[e] = __builtin_amdgcn_mfma_f32_16x16x16f16(af[t], wf, acc[e], 0, 0, 0);
        }
    }

#pragma unroll
    for (int e = 0; e < 4; ++e)
#pragma unroll
        for (int r = 0; r < 4; ++r)
            out[(size_t)(r0 + quad * 4 + r) * E_ + e * 16 + col] = acc[e][r];
}

// ---------------------------------------------------------------------------
extern "C" void kernel_launch(void* const* d_in, const int* in_sizes, int n_in,
                              void* d_out, int out_size, void* d_ws, size_t ws_size,
                              hipStream_t stream) {
    const float* x     = (const float*)d_in[0];   // [8,1024,64] fp32
    const float* theta = (const float*)d_in[1];   // [8]
    const float* W     = (const float*)d_in[2];   // [64,64]
    float* out = (float*)d_out;                   // [8,1024,64]

    _Float16* kG    = (_Float16*)d_ws;                          // 1 MB
    _Float16* vG    = (_Float16*)((char*)d_ws + (2 << 20));     // 1.2 MB
    _Float16* attnH = (_Float16*)((char*)d_ws + (4 << 20));     // 1 MB

    proj_kernel<<<BH * 4, 256, 0, stream>>>(x, theta, kG, vG);
    attn_kernel<<<dim3(BH, S_ / 64), 256, 0, stream>>>(kG, vG, attnH);
    combine_kernel<<<NROW / 16, 64, 0, stream>>>(attnH, W, out);
}